// Round 12
// baseline (24.232 us; speedup 1.0000x reference)
//
#include <hip/hip_runtime.h>

typedef unsigned long long u64;
typedef unsigned int u32;

#define W    4096
#define NT   128
#define CH   32          // one thread per 32-wide chunk (= dist)
#define NCH  128
#define D32  32
#define PSTR 33          // padded row stride (2-way LDS writes = free)
#define PSH  ((NCH + 4) * PSTR)
#define PFXI(c, o) (((c) + 2) * PSTR + (o))
#define SFXI(c, o) (PSH + ((c) + 2) * PSTR + (o))

__global__ __launch_bounds__(NT) void extrema_nms_sb(
    const float* __restrict__ x,
    const int*   __restrict__ dist_p,
    float*       __restrict__ out)
{
    const int sig = blockIdx.x;
    const float* xg = x + (size_t)sig * W;
    float*       og = out + (size_t)sig * W;
    const int dist = *dist_p;

    __shared__ __align__(16) float xs[W];       // 16 KB
    __shared__ __align__(16) u32   PS[2 * PSH]; // PFX | SFX live-window maxima (~35 KB)
    __shared__ u32   KEPT[NCH + 2];             // kept global pos+1, padded, monotone
    __shared__ int   LF;                        // round-stamped pending flag
    __shared__ u64   red[2];                    // fallback only

    const int tid = threadIdx.x;

    // ---- stage x (coalesced float4) + zero pads ----
    {
        const float4* xg4 = (const float4*)xg;
        float4*       xs4 = (float4*)xs;
        #pragma unroll
        for (int v = tid; v < W / 4; v += NT) xs4[v] = xg4[v];
    }
    for (int k = tid; k < 4 * PSTR; k += NT) {  // PS pad rows {0,1,NCH+2,NCH+3}, both halves
        const int rr = k / PSTR, oo = k % PSTR;
        const int row = (rr < 2) ? rr : (NCH + rr);
        PS[row * PSTR + oo] = 0u;
        PS[PSH + row * PSTR + oo] = 0u;
    }
    if (tid < NCH + 2 - NT) KEPT[NT + tid] = 0u;
    KEPT[tid] = 0u;
    if (tid == 0) LF = 0;
    __syncthreads();

    if (dist == D32) {
        const int c = tid, base = tid * CH;

        // ---- extrema keys (u32 (ab<<1)|1; 0 = not extremum). Position ties
        // are resolved structurally: leftmost argmax in-chunk, strict-< vs
        // left neighbors, <= vs right (left ties win, matches stable argsort).
        u32 kb[CH];
        {
            const float4* xs4 = (const float4*)xs;
            float f[CH + 2];
            #pragma unroll
            for (int v = 0; v < 8; ++v) {
                const float4 q = xs4[tid * 8 + v];
                f[4 * v + 1] = q.x; f[4 * v + 2] = q.y;
                f[4 * v + 3] = q.z; f[4 * v + 4] = q.w;
            }
            f[0]      = (tid > 0)      ? xs[base - 1]  : __int_as_float(0x7f800000); // left=true at i=0
            f[CH + 1] = (tid < NT - 1) ? xs[base + CH] : f[CH];                       // right=false at i=W-1
            #pragma unroll
            for (int j = 0; j < CH; ++j) {
                const float xi = f[j + 1];
                const bool right = f[j + 2] > xi;
                const bool left  = xi <= f[j];
                const bool s     = xi <= 0.0f;
                const bool ext   = (right && left && s) || (!right && !left && !s);
                const u32 ab = __float_as_uint(xi) & 0x7fffffffu;
                kb[j] = ext ? ((ab << 1) | 1u) : 0u;
            }
        }
        u32 P = 0;                     // pending mask
        #pragma unroll
        for (int j = 0; j < CH; ++j) if (kb[j]) P |= (1u << j);
        u32 best = 0; int bo = 0;      // in-chunk argmax (leftmost on ties)
        #pragma unroll
        for (int j = 0; j < CH; ++j) if (kb[j] > best) { best = kb[j]; bo = j; }

        // ---- publish helper: live-window prefix/suffix maxima for mask m ----
        #define PUBLISH(m)                                                     \
        do {                                                                   \
            u32 a_ = 0;                                                        \
            _Pragma("unroll")                                                  \
            for (int j = 0; j < CH; ++j) {                                     \
                const u32 kj = (((m) >> j) & 1u) ? kb[j] : 0u;                 \
                a_ = kj > a_ ? kj : a_;                                        \
                PS[PFXI(c, j)] = a_;                                           \
            }                                                                  \
            a_ = 0;                                                            \
            _Pragma("unroll")                                                  \
            for (int j = CH - 1; j >= 0; --j) {                                \
                const u32 kj = (((m) >> j) & 1u) ? kb[j] : 0u;                 \
                a_ = kj > a_ ? kj : a_;                                        \
                PS[SFXI(c, j)] = a_;                                           \
            }                                                                  \
        } while (0)

        PUBLISH(P);                    // initial state; ordered by round-1 barrier
        int kpos = -1;

        // ---- ONE barrier per round ----
        for (int r = 1;; ++r) {
            const u64 bal = __ballot(P != 0u);
            if ((tid & 63) == 0 && bal) LF = r;
            __syncthreads();                       // orders prior publishes + stamps
            if (LF != r) break;                    // uniform: nothing pending anywhere

            if (P) {
                const u32 sl  = PS[SFXI(c - 1, bo)];   // live max over [p-32, base-1]
                const u32 pr  = PS[PFXI(c + 1, bo)];   // live max over [base+32, p+32]
                const u32 kmL = KEPT[c];               // left-kept global pos+1 (monotone)
                const u32 kmR = KEPT[c + 2];           // right-kept global pos+1

                const bool keep_c = (sl < best) && (pr <= best);
                if (keep_c) {
                    KEPT[c + 1] = (u32)(base + bo + 1);
                    kpos = bo;
                    P = 0u;
                    PUBLISH(1u << bo);             // kept candidate blocks forever
                } else {
                    u32 killwin = 0u;
                    if (kmL) {
                        const int e = (int)kmL - 1 - base + D32;      // [0,31]
                        if (e >= 31) killwin = 0xffffffffu;
                        else if (e >= 0) killwin = (1u << (e + 1)) - 1u;
                    }
                    if (kmR) {
                        const int s2 = (int)kmR - 1 - base - D32;     // [0,31]
                        if (s2 <= 0) killwin = 0xffffffffu;
                        else if (s2 <= 31) killwin |= (0xffffffffu << s2);
                    }
                    const u32 newP = P & ~killwin;
                    if (newP != P) {
                        P = newP;
                        if (!((P >> bo) & 1u)) {   // candidate died -> rescan
                            best = 0; bo = 0;
                            #pragma unroll
                            for (int j = 0; j < CH; ++j) {
                                const u32 kj = ((P >> j) & 1u) ? kb[j] : 0u;
                                if (kj > best) { best = kj; bo = j; }
                            }
                        }
                        PUBLISH(P);                // P==0 -> zero rows (unblocks others)
                    }
                }
            }
        }

        // ---- output: 32 elems/thread from LDS + local kept offset ----
        {
            const float4* xs4 = (const float4*)xs;
            float4*       og4 = (float4*)og;
            #pragma unroll
            for (int v = 0; v < 8; ++v) {
                const float4 q = xs4[tid * 8 + v];
                const int j0 = 4 * v;
                float4 o;
                o.x = (kpos == j0    ) ? q.x : 0.0f;
                o.y = (kpos == j0 + 1) ? q.y : 0.0f;
                o.z = (kpos == j0 + 2) ? q.z : 0.0f;
                o.w = (kpos == j0 + 3) ? q.w : 0.0f;
                og4[tid * 8 + v] = o;
            }
        }
    } else {
        // ---------- generic fallback (any dist): proven serial greedy ----------
        u64* SK = (u64*)PS;            // 34.8 KB >= 32 KB, 16B-aligned
        for (int i = tid; i < W; i += NT) og[i] = 0.0f;
        for (int i = tid; i < W; i += NT) {
            const float xi = xs[i];
            const bool right = (i < W - 1) ? (xs[i + 1] > xi) : false;
            const bool left  = (i > 0)     ? (xi <= xs[i - 1]) : true;
            const bool s = (xi <= 0.0f);
            const bool valley = right && left && s;
            const bool peak   = !right && !left && !s;
            const u32 ab = __float_as_uint(xi) & 0x7fffffffu;
            SK[i] = (valley || peak) ? (((u64)ab << 32) | (u64)(u32)(W - 1 - i)) : 0ull;
        }
        __syncthreads();

        for (;;) {
            u64 m = 0ull;
            #pragma unroll
            for (int j = 0; j < W / NT; ++j) {
                const u64 k = SK[tid + j * NT];
                if (k > m) m = k;
            }
            #pragma unroll
            for (int off = 32; off > 0; off >>= 1) {
                const u64 o = __shfl_down(m, off, 64);
                if (o > m) m = o;
            }
            if ((tid & 63) == 0) red[tid >> 6] = m;
            __syncthreads();
            if (tid == 0 && red[1] > red[0]) red[0] = red[1];
            __syncthreads();
            const u64 win = red[0];
            if (win == 0ull) break;

            const int p = (W - 1) - (int)(win & 0xffffffffu);
            if (tid == 0) og[p] = xs[p];

            int lo = p - dist; lo = lo < 0 ? 0 : lo;
            int hi = p + dist; hi = hi > (W - 1) ? (W - 1) : hi;
            for (int j = lo + tid; j <= hi; j += NT) SK[j] = 0ull;
            __syncthreads();
        }
    }
}

extern "C" void kernel_launch(void* const* d_in, const int* in_sizes, int n_in,
                              void* d_out, int out_size, void* d_ws, size_t ws_size,
                              hipStream_t stream) {
    const float* x      = (const float*)d_in[0];
    const int*   dist_p = (const int*)d_in[1];
    float*       out    = (float*)d_out;
    const int nsig = in_sizes[0] / W;   // 128 signals of length 4096
    hipLaunchKernelGGL(extrema_nms_sb, dim3(nsig), dim3(NT), 0, stream,
                       x, dist_p, out);
}

// Round 13
// 17.778 us; speedup vs baseline: 1.3630x; 1.3630x over previous
//
#include <hip/hip_runtime.h>

typedef unsigned long long u64;
typedef unsigned int u32;

#define W    4096
#define NT   128
#define CH   32          // one thread per 32-wide chunk (= dist)
#define NCH  128
#define D32  32
#define RSTR 33          // padded row stride (u32)
#define ROWS (NCH + 4)   // 2 pad rows each side
// PS[buf][arr][row][off]: arr 0 = prefix-max, 1 = suffix-max (u32 keys)
#define PSI(b,a,cc,o) ((((b)*2+(a))*ROWS + ((cc)+2))*RSTR + (o))
#define HMI(b,cc)     ((b)*ROWS + ((cc)+2))

__global__ __launch_bounds__(NT) void extrema_nms_db(
    const float* __restrict__ x,
    const int*   __restrict__ dist_p,
    float*       __restrict__ out)
{
    const int sig = blockIdx.x;
    const float* xg = x + (size_t)sig * W;
    float*       og = out + (size_t)sig * W;
    const int dist = *dist_p;
    const int tid  = threadIdx.x;

    __shared__ __align__(16) u32 PS[4 * ROWS * RSTR];  // ~68 KB (fallback aliases into this)
    __shared__ u64 HM[2 * ROWS];                        // chunk candidates (key<<32|pos)
    __shared__ int LF;                                  // round-stamped live flag

    if (dist == D32) {
        const int base = tid * CH;

        // ---- zero pad rows (both bufs/arrays) + HM pads ----
        for (int k = tid; k < 4 * 4 * RSTR; k += NT) {
            const int grp = k / (4 * RSTR);            // (buf,arr)
            const int rem = k % (4 * RSTR);
            const int prw = rem / RSTR;                // pad row 0..3
            const int oo  = rem % RSTR;
            const int cc  = (prw < 2) ? (prw - 2) : (NCH + prw - 2);
            PS[PSI(grp >> 1, grp & 1, cc, oo)] = 0u;
        }
        if (tid < 2) {
            HM[HMI(0, tid - 2)] = 0ull; HM[HMI(0, NCH + tid)] = 0ull;
            HM[HMI(1, tid - 2)] = 0ull; HM[HMI(1, NCH + tid)] = 0ull;
        }

        // ---- input in registers; 2 scalar boundary loads ----
        float f[CH + 2];
        {
            const float4* xg4 = (const float4*)xg + tid * 8;
            #pragma unroll
            for (int v = 0; v < 8; ++v) {
                const float4 q = xg4[v];
                f[4*v+1] = q.x; f[4*v+2] = q.y; f[4*v+3] = q.z; f[4*v+4] = q.w;
            }
            f[0]      = (tid > 0)      ? xg[base - 1]  : __int_as_float(0x7f800000); // left=true at i=0
            f[CH + 1] = (tid < NT - 1) ? xg[base + CH] : f[CH];                       // right=false at i=W-1
        }
        u32 kb[CH];
        #pragma unroll
        for (int j = 0; j < CH; ++j) {
            const float xi = f[j + 1];
            const bool right = f[j + 2] > xi;
            const bool left  = xi <= f[j];
            const bool s     = xi <= 0.0f;
            const bool ext   = (right && left && s) || (!right && !left && !s);
            const u32 ab = __float_as_uint(xi) & 0x7fffffffu;
            kb[j] = ext ? ((ab << 1) | 1u) : 0u;
        }
        u32 P = 0;
        #pragma unroll
        for (int j = 0; j < CH; ++j) if (kb[j]) P |= 1u << j;
        u32 best = 0; int bo = 0;          // leftmost argmax = highest priority
        #pragma unroll
        for (int j = 0; j < CH; ++j) if (kb[j] > best) { best = kb[j]; bo = j; }

        // publish my chunk state (live prefix/suffix maxima + candidate) to buffer b
        auto publish = [&](int b) {
            u32 a = 0;
            #pragma unroll
            for (int j = 0; j < CH; ++j) {
                const u32 kj = ((P >> j) & 1u) ? kb[j] : 0u;
                a = kj > a ? kj : a;
                PS[PSI(b, 0, tid, j)] = a;
            }
            a = 0;
            #pragma unroll
            for (int j = CH - 1; j >= 0; --j) {
                const u32 kj = ((P >> j) & 1u) ? kb[j] : 0u;
                a = kj > a ? kj : a;
                PS[PSI(b, 1, tid, j)] = a;
            }
            HM[HMI(b, tid)] = best ? (((u64)best << 32) | (u32)(base + bo)) : 0ull;
        };
        publish(0); publish(1);            // S(0) into both buffers
        {
            const u64 bal = __ballot(P != 0u);
            if ((tid & 63) == 0 && bal) LF = 1;   // stamp round 1 (garbage-tolerant if none live)
        }
        int  kpos = -1;
        bool chgPrev = false;

        // ---- ONE barrier per generation; reads from buf[(r-1)&1], writes buf[r&1] ----
        for (int r = 1;; ++r) {
            __syncthreads();               // orders prev round's publishes + LF stamp
            const int pb = (r - 1) & 1;
            const int lf = LF;
            const u64 hL = HM[HMI(pb, tid - 1)];     // c-1 candidate of S(r-1)
            const u64 hR = HM[HMI(pb, tid + 1)];     // c+1 candidate
            u32 sl = 0, pr = 0;
            if (P) {                                  // own keeper test inputs (bo local)
                sl = PS[PSI(pb, 1, tid - 1, bo)];     // live max over [p-32, base-1]
                pr = PS[PSI(pb, 0, tid + 1, bo)];     // live max over [base+32, p+32]
            }
            if (lf != r) break;                       // uniform: nothing live in S(r-1)

            bool chg = false;
            if (P) {
                const bool keep_c = (sl < best) && (pr <= best); // left ties win
                const u32 ML = (u32)(hL >> 32); const int pL = (int)(u32)hL;
                const u32 MR = (u32)(hR >> 32); const int pR = (int)(u32)hR;
                bool keep_m = false, keep_p = false;
                if (ML) {                              // keeper(c-1): same rule, its frame
                    const int boL = pL + D32 - base;   // in [0,31]
                    const u32 sl2 = PS[PSI(pb, 1, tid - 2, boL)];
                    const u32 pr2 = PS[PSI(pb, 0, tid,     boL)];
                    keep_m = (sl2 < ML) && (pr2 <= ML);
                }
                if (MR) {                              // keeper(c+1)
                    const int boR = pR - D32 - base;   // in [0,31]
                    const u32 sl3 = PS[PSI(pb, 1, tid,     boR)];
                    const u32 pr3 = PS[PSI(pb, 0, tid + 2, boR)];
                    keep_p = (sl3 < MR) && (pr3 <= MR);
                }
                u32 newP = P;
                if (keep_m) {                          // kill positions <= pL+32
                    const int e = pL + D32 - base;     // [0,31]
                    newP &= (e >= 31) ? 0u : ~((1u << (e + 1)) - 1u);
                }
                if (keep_p) {                          // kill positions >= pR-32
                    const int s2 = pR - D32 - base;    // [0,31]
                    newP &= (s2 <= 0) ? 0u : ~(0xffffffffu << s2);
                }
                if (keep_c) { kpos = bo; newP = 0u; }  // keeper kills own whole chunk
                if (newP != P) {
                    P = newP; chg = true;
                    if (!((P >> bo) & 1u)) {           // candidate died -> rescan
                        best = 0; bo = 0;
                        #pragma unroll
                        for (int j = 0; j < CH; ++j) {
                            const u32 kj = ((P >> j) & 1u) ? kb[j] : 0u;
                            if (kj > best) { best = kj; bo = j; }
                        }
                    }
                }
            }
            if (chg || chgPrev) publish(r & 1);        // keep buf[r&1] == S(r)
            chgPrev = chg;
            const u64 bal = __ballot(P != 0u);
            if ((tid & 63) == 0 && bal) LF = r + 1;    // stamp next round
        }

        // ---- output straight from registers ----
        {
            float4* og4 = (float4*)og + tid * 8;
            #pragma unroll
            for (int v = 0; v < 8; ++v) {
                const int j0 = 4 * v;
                float4 o;
                o.x = (kpos == j0    ) ? f[j0 + 1] : 0.0f;
                o.y = (kpos == j0 + 1) ? f[j0 + 2] : 0.0f;
                o.z = (kpos == j0 + 2) ? f[j0 + 3] : 0.0f;
                o.w = (kpos == j0 + 3) ? f[j0 + 4] : 0.0f;
                og4[v] = o;
            }
        }
    } else {
        // ---------- generic fallback (any dist): proven serial greedy, NT=128 ----------
        u64* SK  = (u64*)PS;               // 32 KB alias
        u64* red = HM;                     // 2-wave reduction scratch
        for (int i = tid; i < W; i += NT) og[i] = 0.0f;
        for (int i = tid; i < W; i += NT) {
            const float xi = xg[i];
            const bool right = (i < W - 1) ? (xg[i + 1] > xi) : false;
            const bool left  = (i > 0)     ? (xi <= xg[i - 1]) : true;
            const bool s = (xi <= 0.0f);
            const bool valley = right && left && s;
            const bool peak   = !right && !left && !s;
            const u32 ab = __float_as_uint(xi) & 0x7fffffffu;
            SK[i] = (valley || peak) ? (((u64)ab << 32) | (u64)(u32)(W - 1 - i)) : 0ull;
        }
        __syncthreads();

        for (;;) {
            u64 m = 0ull;
            #pragma unroll
            for (int j = 0; j < W / NT; ++j) {
                const u64 k = SK[tid + j * NT];
                if (k > m) m = k;
            }
            #pragma unroll
            for (int off = 32; off > 0; off >>= 1) {
                const u64 o = __shfl_down(m, off, 64);
                if (o > m) m = o;
            }
            if ((tid & 63) == 0) red[tid >> 6] = m;
            __syncthreads();
            if (tid == 0 && red[1] > red[0]) red[0] = red[1];
            __syncthreads();
            const u64 win = red[0];
            if (win == 0ull) break;

            const int p = (W - 1) - (int)(win & 0xffffffffu);
            if (tid == 0) og[p] = xg[p];

            int lo = p - dist; lo = lo < 0 ? 0 : lo;
            int hi = p + dist; hi = hi > (W - 1) ? (W - 1) : hi;
            for (int j = lo + tid; j <= hi; j += NT) SK[j] = 0ull;
            __syncthreads();
        }
    }
}

extern "C" void kernel_launch(void* const* d_in, const int* in_sizes, int n_in,
                              void* d_out, int out_size, void* d_ws, size_t ws_size,
                              hipStream_t stream) {
    const float* x      = (const float*)d_in[0];
    const int*   dist_p = (const int*)d_in[1];
    float*       out    = (float*)d_out;
    const int nsig = in_sizes[0] / W;   // 128 signals of length 4096
    hipLaunchKernelGGL(extrema_nms_db, dim3(nsig), dim3(NT), 0, stream,
                       x, dist_p, out);
}